// Round 9
// baseline (227.751 us; speedup 1.0000x reference)
//
#include <hip/hip_runtime.h>
#include <hip/hip_bf16.h>
#include <cstdint>

#define TT 243
#define NJ 17
#define NB 4
#define NH 8
#define HD 64
#define CDIM 512
#define NROWS (NB*TT*NJ)   // 16524
#define NBHN (NB*NH*NJ)    // 544

typedef unsigned short u16;
typedef __attribute__((ext_vector_type(8))) short short8;
typedef __attribute__((ext_vector_type(4))) float f32x4;

#define MFMA16(a, b, c) __builtin_amdgcn_mfma_f32_16x16x32_bf16((a), (b), (c), 0, 0, 0)
#define QSCALE 0.18033688011112042f   // 0.125 * log2(e): scores in log2 domain

__device__ __forceinline__ void gl_lds16(const void* g, void* l) {
  __builtin_amdgcn_global_load_lds(
      (const __attribute__((address_space(1))) void*)g,
      (__attribute__((address_space(3))) void*)l, 16, 0, 0);
}

__device__ __forceinline__ u16 f2bf(float f) {
  union { float f; unsigned u; } v; v.f = f;
  unsigned r = v.u + 0x7FFFu + ((v.u >> 16) & 1u);
  return (u16)(r >> 16);
}

__device__ __forceinline__ float fast_exp2(float x) {
#if __has_builtin(__builtin_amdgcn_exp2f)
  return __builtin_amdgcn_exp2f(x);
#else
  return exp2f(x);
#endif
}
__device__ __forceinline__ float fast_rcp(float x) {
#if __has_builtin(__builtin_amdgcn_rcpf)
  return __builtin_amdgcn_rcpf(x);
#else
  return 1.f / x;
#endif
}
__device__ __forceinline__ unsigned pk_bf16(float a, float b) {
#if __has_builtin(__builtin_amdgcn_cvt_pk_bf16_f32)
  auto pk = __builtin_amdgcn_cvt_pk_bf16_f32(a, b);
  unsigned u; __builtin_memcpy(&u, &pk, sizeof(u));
  return u;
#else
  return (unsigned)f2bf(a) | ((unsigned)f2bf(b) << 16);
#endif
}

// ---------------- prep: weight transposes only ----------------
#define T1_NB 48
#define T1_BLOCKS (48 * 16)                  // qkv_w 512x1536
#define T2_NB 16
#define T2_BLOCKS (16 * 16)                  // proj_w 512x512

__device__ __forceinline__ void trans_body(const float* __restrict__ in,
                                           u16* __restrict__ out, int K, int N,
                                           int nb, int kb, float (*tile)[33]) {
  int n0 = nb * 32, k0 = kb * 32;
  int tx = threadIdx.x & 31, ty = threadIdx.x >> 5;
#pragma unroll
  for (int p = 0; p < 4; ++p)
    tile[ty + p * 8][tx] = in[(size_t)(k0 + ty + p * 8) * N + n0 + tx];
  __syncthreads();
#pragma unroll
  for (int p = 0; p < 4; ++p)
    out[(size_t)(n0 + ty + p * 8) * K + k0 + tx] = f2bf(tile[tx][ty + p * 8]);
}

__global__ __launch_bounds__(256) void prep_kernel(
    const float* __restrict__ qkv_w, const float* __restrict__ proj_w,
    const float* __restrict__ te_w, u16* __restrict__ wt,
    u16* __restrict__ pwt, u16* __restrict__ tewt) {
  __shared__ float tile[32][33];
  int bid = blockIdx.x;
  if (bid < T1_BLOCKS) {
    trans_body(qkv_w, wt, 512, 1536, bid % T1_NB, bid / T1_NB, tile);
  } else if (bid < T1_BLOCKS + T2_BLOCKS) {
    int r = bid - T1_BLOCKS;
    trans_body(proj_w, pwt, 512, 512, r % T2_NB, r / T2_NB, tile);
  } else {
    // te_w [512][4] fp32 -> tewt [4][512] bf16
#pragma unroll
    for (int i = 0; i < 8; ++i) {
      int idx = threadIdx.x + i * 256;
      int e = idx >> 9, c = idx & 511;
      tewt[idx] = f2bf(te_w[(size_t)c * 4 + e]);
    }
  }
}

// ---------------- qkv GEMM (bf16 MFMA), BK=64, A staged from fp32 x with in-flight cvt;
// grid (13, 130): bx<12 = GEMM n-blocks (n-fastest), bx==12 = gates path ----------------
__global__ __launch_bounds__(256) void qkv_gemm(
    const float* __restrict__ xf, const u16* __restrict__ wt,
    const u16* __restrict__ tewt, const float* __restrict__ te_b,
    u16* __restrict__ qh, u16* __restrict__ kh, u16* __restrict__ vb,
    float* __restrict__ gates) {
  __shared__ u16 S[16640];   // A [0,8192) + B [8192,16384) | V-transpose stride 130
  u16* Al = S;
  u16* Bl = S + 8192;
  int tid = threadIdx.x;
  int w = tid >> 6;
  int c16 = tid & 15, g4 = (tid >> 4) & 3;
  int r0 = blockIdx.y * 128;
  int bx = blockIdx.x;
  int rA = tid >> 3;
  int c8e = (((tid & 7) ^ (rA & 7)) * 8);   // element offset of swizzled chunk

  // A source rows (M permuted to (b,j,t)), fp32 element offsets
  size_t arow4[4];
#pragma unroll
  for (int it = 0; it < 4; ++it) {
    int m = r0 + it * 32 + rA;
    if (m >= NROWS) m = NROWS - 1;
    int bj = m / 243, t = m - bj * 243;
    int b = bj / 17, j = bj - b * 17;
    arow4[it] = ((size_t)(b * 243 + t) * 17 + j) * 512;
  }

  if (bx == 12) {
    // ======== gates path: logits = x @ te_w, softmax over 4 ========
    u16* Tl = Bl;   // [16 rows][64 k] u16, rows 4..15 stay zero
    *(uint2*)(Tl + tid * 4) = make_uint2(0u, 0u);
    f32x4 gacc[2] = {};
    for (int k0 = 0; k0 < CDIM; k0 += 64) {
      __syncthreads();
      float4 fa[4][2];
#pragma unroll
      for (int it = 0; it < 4; ++it) {
        const float* src = xf + arow4[it] + k0 + c8e;
        fa[it][0] = *(const float4*)(src);
        fa[it][1] = *(const float4*)(src + 4);
      }
#pragma unroll
      for (int it = 0; it < 4; ++it) {
        uint4 pkv;
        pkv.x = pk_bf16(fa[it][0].x, fa[it][0].y);
        pkv.y = pk_bf16(fa[it][0].z, fa[it][0].w);
        pkv.z = pk_bf16(fa[it][1].x, fa[it][1].y);
        pkv.w = pk_bf16(fa[it][1].z, fa[it][1].w);
        *(uint4*)(Al + (size_t)(it * 256 + tid) * 8) = pkv;
      }
      if (tid < 32) {
        int row = tid >> 3;
        gl_lds16(tewt + (size_t)row * 512 + k0 + (((tid & 7) ^ row) * 8), Tl);
      }
      __syncthreads();
      short8 tf[2];
#pragma unroll
      for (int hh = 0; hh < 2; ++hh)
        tf[hh] = *(const short8*)(Tl + c16 * 64 + (((hh * 4 + g4) ^ (c16 & 7)) * 8));
#pragma unroll
      for (int i2 = 0; i2 < 2; ++i2) {
        int rowa = w * 32 + i2 * 16 + c16;
#pragma unroll
        for (int hh = 0; hh < 2; ++hh) {
          short8 af = *(const short8*)(Al + rowa * 64 + (((hh * 4 + g4) ^ (c16 & 7)) * 8));
          gacc[i2] = MFMA16(af, tf[hh], gacc[i2]);
        }
      }
    }
    float bias = (c16 < 4) ? te_b[c16 & 3] : 0.f;
#pragma unroll
    for (int i2 = 0; i2 < 2; ++i2)
#pragma unroll
      for (int r = 0; r < 4; ++r) {
        int m = r0 + w * 32 + i2 * 16 + g4 * 4 + r;
        if (m >= NROWS) continue;
        float v = gacc[i2][r] + bias;
        float mx = fmaxf(v, __shfl_xor(v, 1, 64));
        mx = fmaxf(mx, __shfl_xor(mx, 2, 64));
        float e = __expf(v - mx);
        float sum = e + __shfl_xor(e, 1, 64);
        sum += __shfl_xor(sum, 2, 64);
        if (c16 < 4) {
          int bj = m / 243, t = m - bj * 243;
          int b = bj / 17, j = bj - b * 17;
          gates[((size_t)(b * 243 + t) * 17 + j) * 4 + c16] = e * fast_rcp(sum);
        }
      }
    return;
  }

  // ======== main GEMM path ========
  int n0 = bx * 128;
  int wm = w & 1, wn = w >> 1;
  size_t brow4[4];
#pragma unroll
  for (int it = 0; it < 4; ++it)
    brow4[it] = (size_t)(n0 + it * 32 + rA) * 512;

  f32x4 acc[4][4] = {};
  for (int k0 = 0; k0 < CDIM; k0 += 64) {
    __syncthreads();
    float4 fa[4][2];
#pragma unroll
    for (int it = 0; it < 4; ++it) {
      const float* src = xf + arow4[it] + k0 + c8e;
      fa[it][0] = *(const float4*)(src);
      fa[it][1] = *(const float4*)(src + 4);
    }
#pragma unroll
    for (int it = 0; it < 4; ++it) {
      gl_lds16(wt + brow4[it] + k0 + c8e, Bl + (size_t)(it * 256 + (w * 64)) * 8);
      uint4 pkv;
      pkv.x = pk_bf16(fa[it][0].x, fa[it][0].y);
      pkv.y = pk_bf16(fa[it][0].z, fa[it][0].w);
      pkv.z = pk_bf16(fa[it][1].x, fa[it][1].y);
      pkv.w = pk_bf16(fa[it][1].z, fa[it][1].w);
      *(uint4*)(Al + (size_t)(it * 256 + tid) * 8) = pkv;
    }
    __syncthreads();
    short8 af[4][2], bf[4][2];
#pragma unroll
    for (int i = 0; i < 4; ++i) {
      int rowa = wm * 64 + i * 16 + c16;
#pragma unroll
      for (int hh = 0; hh < 2; ++hh)
        af[i][hh] = *(const short8*)(Al + rowa * 64 + (((hh * 4 + g4) ^ (c16 & 7)) * 8));
    }
#pragma unroll
    for (int j = 0; j < 4; ++j) {
      int rowb = wn * 64 + j * 16 + c16;
#pragma unroll
      for (int hh = 0; hh < 2; ++hh)
        bf[j][hh] = *(const short8*)(Bl + rowb * 64 + (((hh * 4 + g4) ^ (c16 & 7)) * 8));
    }
#pragma unroll
    for (int i = 0; i < 4; ++i)
#pragma unroll
      for (int j = 0; j < 4; ++j) {
        acc[i][j] = MFMA16(af[i][0], bf[j][0], acc[i][j]);
        acc[i][j] = MFMA16(af[i][1], bf[j][1], acc[i][j]);
      }
  }

  if (n0 < 1024) {
    // ---- q/k epilogue: direct store to [bhn][t][64]; q pre-scaled by QSCALE
#pragma unroll
    for (int i = 0; i < 4; ++i)
#pragma unroll
      for (int r = 0; r < 4; ++r) {
        int m = r0 + wm * 64 + i * 16 + g4 * 4 + r;
        if (m >= NROWS) continue;
        int bj = m / 243, t = m - bj * 243;
        int b = bj / 17, j = bj - b * 17;
#pragma unroll
        for (int jt = 0; jt < 4; ++jt) {
          int col = n0 + wn * 64 + jt * 16 + c16;
          int sel = col >> 9, h = (col >> 6) & 7, c = col & 63;
          u16* dst = sel ? kh : qh;
          float val = acc[i][jt][r];
          if (!sel) val *= QSCALE;
          dst[((size_t)((b * 8 + h) * 17 + j) * 243 + t) * 64 + c] = f2bf(val);
        }
      }
  } else {
    // ---- V epilogue: transpose C-tile via LDS, store t-contiguous
    __syncthreads();
#pragma unroll
    for (int i = 0; i < 4; ++i)
#pragma unroll
      for (int jt = 0; jt < 4; ++jt)
#pragma unroll
        for (int r = 0; r < 4; ++r) {
          int row = wm * 64 + i * 16 + g4 * 4 + r;
          int colI = wn * 64 + jt * 16 + c16;
          S[colI * 130 + row] = f2bf(acc[i][jt][r]);
        }
    __syncthreads();
    int l = tid & 63;
    int hb = (n0 - 1024) >> 6;
    int m0 = r0 + 2 * l;
    int m1 = m0 + 1;
    bool v0 = m0 < NROWS, v1 = m1 < NROWS;
    int bj0 = m0 / 243, t0 = m0 - bj0 * 243;
    int b0 = bj0 / 17, j0 = bj0 - b0 * 17;
    int bj1 = m1 / 243, t1 = m1 - bj1 * 243;
    int b1 = bj1 / 17, j1 = bj1 - b1 * 17;
    size_t base0 = ((size_t)(b0 * 136 + j0) * 64) * 256 + t0;
    size_t base1 = ((size_t)(b1 * 136 + j1) * 64) * 256 + t1;
#pragma unroll 8
    for (int cc = 0; cc < 32; ++cc) {
      int colI = w * 32 + cc;
      int h = hb + (colI >> 6), c = colI & 63;
      ushort2 u = *(const ushort2*)&S[colI * 130 + 2 * l];
      size_t hoff = ((size_t)h * 17 * 64) * 256 + (size_t)c * 256;
      if (v0) vb[base0 + hoff] = u.x;
      if (v1) vb[base1 + hoff] = u.y;
    }
  }
}

// ---------------- fused attention (bf16 MFMA), S^T orientation ----------------
__global__ __launch_bounds__(256, 4) void attn_kernel(
    const u16* __restrict__ qh, const u16* __restrict__ kh,
    const u16* __restrict__ vb, const float* __restrict__ gates,
    u16* __restrict__ preb) {
  __shared__ u16 L[16384];
  int bhn = blockIdx.x;
  int q0 = blockIdx.y * 64;
  int b = bhn / (NH * NJ);
  int hj = bhn - b * (NH * NJ);
  int h = hj / NJ, j = hj - h * NJ;
  int tid = threadIdx.x;
  int w = tid >> 6;
  int c16 = tid & 15, g4 = (tid >> 4) & 3;
  const u16* Kp = kh + (size_t)bhn * (TT * HD);
  const u16* Qp = qh + (size_t)bhn * (TT * HD);
  const u16* Vp = vb + (size_t)bhn * (HD * 256);
  u16* Rw = L + w * 4096;

  // ---- stage K once, xor-swizzled
#pragma unroll
  for (int it = 0; it < 8; ++it) {
    int F = it * 256 + tid;
    int s = F >> 3;
    int c8 = (F & 7) ^ (s & 7);
    int sg = s < TT ? s : TT - 1;
    gl_lds16(Kp + (size_t)sg * 64 + c8 * 8, L + (size_t)(it * 256 + (tid & ~63)) * 8);
  }
  __syncthreads();   // barrier 1

  int tt = q0 + w * 16 + c16;
  bool tvalid = tt < TT;
  int tg = tvalid ? tt : TT - 1;

  short8 bq[2];
#pragma unroll
  for (int hh = 0; hh < 2; ++hh)
    bq[hh] = *(const short8*)(Qp + (size_t)tg * 64 + hh * 32 + g4 * 8);

  f32x4 acc[16];
#pragma unroll
  for (int st = 0; st < 16; ++st) acc[st] = (f32x4)(0.f);
#pragma unroll
  for (int st = 0; st < 16; ++st) {
    int sf = st * 16 + c16;
#pragma unroll
    for (int hh = 0; hh < 2; ++hh) {
      short8 ak = *(const short8*)(L + sf * 64 + ((hh * 4 + g4) ^ (sf & 7)) * 8);
      acc[st] = MFMA16(ak, bq[hh], acc[st]);
    }
  }
  __syncthreads();   // barrier 2: L becomes R region

  // ---- mask the st=15 tail (s = 240 + g4*4 + r >= 243)
#pragma unroll
  for (int r = 0; r < 4; ++r) {
    int s = 240 + g4 * 4 + r;
    if (s >= TT) acc[15][r] = -1e30f;
  }
  // ---- row max
  float M = -1e30f;
#pragma unroll
  for (int st = 0; st < 16; ++st)
#pragma unroll
    for (int r = 0; r < 4; ++r) M = fmaxf(M, acc[st][r]);
  M = fmaxf(M, __shfl_xor(M, 16, 64));
  M = fmaxf(M, __shfl_xor(M, 32, 64));

  // ---- exp2 (scores already in log2 domain)
#pragma unroll
  for (int st = 0; st < 16; ++st)
#pragma unroll
    for (int r = 0; r < 4; ++r) acc[st][r] = fast_exp2(acc[st][r] - M);

  // ---- nested-window sums: l243 via vector tree, others masked into f32x4 lanes
  int t9b = (tg / 9) * 9;
  int t27b = (tg / 27) * 27;
  int t81b = (tg / 81) * 81;
  f32x4 vall = acc[0];
#pragma unroll
  for (int st = 1; st < 16; ++st) vall += acc[st];
  float l243 = (vall[0] + vall[1]) + (vall[2] + vall[3]);
  f32x4 v81 = (f32x4)(0.f), v27 = (f32x4)(0.f), v9 = (f32x4)(0.f);
#pragma unroll
  for (int st = 0; st < 16; ++st)
#pragma unroll
    for (int r = 0; r < 4; ++r) {
      int s = st * 16 + g4 * 4 + r;
      float e = acc[st][r];
      v81[r] += ((unsigned)(s - t81b) < 81u) ? e : 0.f;
      v27[r] += ((unsigned)(s - t27b) < 27u) ? e : 0.f;
      v9[r]  += ((unsigned)(s - t9b)  <  9u) ? e : 0.f;
    }
  float l81 = (v81[0] + v81[1]) + (v81[2] + v81[3]);
  float l27 = (v27[0] + v27[1]) + (v27[2] + v27[3]);
  float l9  = (v9[0] + v9[1]) + (v9[2] + v9[3]);
  l9   += __shfl_xor(l9, 16, 64);   l9   += __shfl_xor(l9, 32, 64);
  l27  += __shfl_xor(l27, 16, 64);  l27  += __shfl_xor(l27, 32, 64);
  l81  += __shfl_xor(l81, 16, 64);  l81  += __shfl_xor(l81, 32, 64);
  l243 += __shfl_xor(l243, 16, 64); l243 += __shfl_xor(l243, 32, 64);

  float4 gv = *(const float4*)(gates + ((size_t)(b * TT + tg) * NJ + j) * 4);
  float gam3 = gv.w * fast_rcp(l243);
  float gam2 = gam3 + gv.z * fast_rcp(l81);
  float gam1 = gam2 + gv.y * fast_rcp(l27);
  float gam0 = gam1 + gv.x * fast_rcp(l9);
  if (!tvalid) { gam0 = 0.f; gam1 = 0.f; gam2 = 0.f; gam3 = 0.f; }

  // ---- combined weights R[t][s] -> wave-private LDS, packed b64 writes
#pragma unroll
  for (int st = 0; st < 16; ++st) {
    float rv[4];
#pragma unroll
    for (int r = 0; r < 4; ++r) {
      int s = st * 16 + g4 * 4 + r;
      float e = acc[st][r];
      float cw = ((unsigned)(s - t9b) < 9u) ? gam0
               : ((unsigned)(s - t27b) < 27u) ? gam1
               : ((unsigned)(s - t81b) < 81u) ? gam2 : gam3;
      rv[r] = e * cw;
    }
    uint2 pk;
    pk.x = pk_bf16(rv[0], rv[1]);
    pk.y = pk_bf16(rv[2], rv[3]);
    int c8 = st * 2 + (g4 >> 1);
    int slot = (c8 & 24) | ((c8 & 7) ^ (c16 & 7));
    *(uint2*)(Rw + c16 * 256 + slot * 8 + (g4 & 1) * 4) = pk;
  }
  // no barrier: Rw is wave-private

  // ---- PV: O[16t][64c] = R[16][256] @ V[256][64]
  short8 ar[8];
#pragma unroll
  for (int h2 = 0; h2 < 8; ++h2) {
    int cc = h2 * 4 + g4;
    int slot = (cc & 24) | ((cc & 7) ^ (c16 & 7));
    ar[h2] = *(const short8*)(Rw + c16 * 256 + slot * 8);
  }
#pragma unroll
  for (int jt = 0; jt < 4; ++jt) {
    int c = jt * 16 + c16;
    f32x4 o = (f32x4)(0.f);
#pragma unroll
    for (int h2 = 0; h2 < 8; ++h2) {
      short8 bv = *(const short8*)(Vp + (size_t)c * 256 + h2 * 32 + g4 * 8);
      o = MFMA16(ar[h2], bv, o);
    }
#pragma unroll
    for (int r = 0; r < 4; ++r) {
      int t = q0 + w * 16 + g4 * 4 + r;
      if (t < TT)
        preb[((size_t)(b * TT + t) * NJ + j) * 512 + h * 64 + c] = f2bf(o[r]);
    }
  }
}

// ---------------- proj GEMM (bf16 MFMA), BK=64, + bias, fp32 out, n-fastest ----------------
__global__ __launch_bounds__(256) void proj_gemm(
    const u16* __restrict__ preb, const u16* __restrict__ pwt,
    const float* __restrict__ bias, float* __restrict__ out) {
  __shared__ u16 Al[8192];
  __shared__ u16 Bl[8192];
  int tid = threadIdx.x;
  int w = tid >> 6;
  int c16 = tid & 15, g4 = (tid >> 4) & 3;
  int r0 = blockIdx.y * 128, n0 = blockIdx.x * 128;
  int wm = w & 1, wn = w >> 1;

  int rA = tid >> 3;
  int c8off = (((tid & 7) ^ (rA & 7)) * 8);
  size_t arow4[4], brow4[4];
#pragma unroll
  for (int it = 0; it < 4; ++it) {
    int m = r0 + it * 32 + rA;
    if (m >= NROWS) m = NROWS - 1;
    arow4[it] = (size_t)m * 512;
    brow4[it] = (size_t)(n0 + it * 32 + rA) * 512;
  }

  f32x4 acc[4][4] = {};
  for (int k0 = 0; k0 < CDIM; k0 += 64) {
    __syncthreads();
#pragma unroll
    for (int it = 0; it < 4; ++it) {
      gl_lds16(preb + arow4[it] + k0 + c8off, Al + (size_t)(it * 256 + (w * 64)) * 8);
      gl_lds16(pwt + brow4[it] + k0 + c8off, Bl + (size_t)(it * 256 + (w * 64)) * 8);
    }
    __syncthreads();
    short8 af[4][2], bf[4][2];
#pragma unroll
    for (int i = 0; i < 4; ++i) {
      int rowa = wm * 64 + i * 16 + c16;
#pragma unroll
      for (int hh = 0; hh < 2; ++hh)
        af[i][hh] = *(const short8*)(Al + rowa * 64 + (((hh * 4 + g4) ^ (c16 & 7)) * 8));
    }
#pragma unroll
    for (int j = 0; j < 4; ++j) {
      int rowb = wn * 64 + j * 16 + c16;
#pragma unroll
      for (int hh = 0; hh < 2; ++hh)
        bf[j][hh] = *(const short8*)(Bl + rowb * 64 + (((hh * 4 + g4) ^ (c16 & 7)) * 8));
    }
#pragma unroll
    for (int i = 0; i < 4; ++i)
#pragma unroll
      for (int j = 0; j < 4; ++j) {
        acc[i][j] = MFMA16(af[i][0], bf[j][0], acc[i][j]);
        acc[i][j] = MFMA16(af[i][1], bf[j][1], acc[i][j]);
      }
  }
#pragma unroll
  for (int i = 0; i < 4; ++i)
#pragma unroll
    for (int r = 0; r < 4; ++r) {
      int row = r0 + wm * 64 + i * 16 + g4 * 4 + r;
      if (row >= NROWS) continue;
#pragma unroll
      for (int jt = 0; jt < 4; ++jt) {
        int col = n0 + wn * 64 + jt * 16 + c16;
        out[(size_t)row * 512 + col] = acc[i][jt][r] + bias[col];
      }
    }
}

extern "C" void kernel_launch(void* const* d_in, const int* in_sizes, int n_in,
                              void* d_out, int out_size, void* d_ws, size_t ws_size,
                              hipStream_t stream) {
  (void)in_sizes; (void)n_in; (void)out_size; (void)ws_size;
  const float* x      = (const float*)d_in[0];
  const float* qkv_w  = (const float*)d_in[1];
  const float* proj_w = (const float*)d_in[2];
  const float* proj_b = (const float*)d_in[3];
  const float* te_w   = (const float*)d_in[4];
  const float* te_b   = (const float*)d_in[5];

  char* p = (char*)d_ws;
  auto alloc = [&](size_t bytes) {
    void* r = (void*)p;
    p += (bytes + 255) & ~(size_t)255;
    return r;
  };
  u16*   wt    = (u16*)alloc((size_t)1536 * 512 * 2);
  u16*   pwt   = (u16*)alloc((size_t)512 * 512 * 2);
  u16*   tewt  = (u16*)alloc((size_t)4 * 512 * 2);
  float* gates = (float*)alloc((size_t)NROWS * 4 * 4);
  u16*   qhb   = (u16*)alloc((size_t)NBHN * 243 * 64 * 2);
  u16*   khb   = (u16*)alloc((size_t)NBHN * 243 * 64 * 2);
  u16*   vb    = (u16*)alloc((size_t)NBHN * 64 * 256 * 2);
  u16*   preb  = (u16*)alloc((size_t)NROWS * 512 * 2);
  float* out   = (float*)d_out;

  hipLaunchKernelGGL(prep_kernel, dim3(T1_BLOCKS + T2_BLOCKS + 1), dim3(256), 0, stream,
                     qkv_w, proj_w, te_w, wt, pwt, tewt);
  hipLaunchKernelGGL(qkv_gemm, dim3(13, (NROWS + 127) / 128), dim3(256), 0, stream,
                     x, wt, tewt, te_b, qhb, khb, vb, gates);
  hipLaunchKernelGGL(attn_kernel, dim3(NBHN, 4), dim3(256), 0, stream,
                     qhb, khb, vb, gates, preb);
  hipLaunchKernelGGL(proj_gemm, dim3(4, (NROWS + 127) / 128), dim3(256), 0, stream,
                     preb, pwt, proj_b, out);
}

// Round 10
// 212.642 us; speedup vs baseline: 1.0711x; 1.0711x over previous
//
#include <hip/hip_runtime.h>
#include <hip/hip_bf16.h>
#include <cstdint>

#define TT 243
#define NJ 17
#define NB 4
#define NH 8
#define HD 64
#define CDIM 512
#define NROWS (NB*TT*NJ)   // 16524
#define NBHN (NB*NH*NJ)    // 544

typedef unsigned short u16;
typedef __attribute__((ext_vector_type(8))) short short8;
typedef __attribute__((ext_vector_type(4))) float f32x4;

#define MFMA16(a, b, c) __builtin_amdgcn_mfma_f32_16x16x32_bf16((a), (b), (c), 0, 0, 0)
#define QSCALE 0.18033688011112042f   // 0.125 * log2(e): scores in log2 domain

__device__ __forceinline__ void gl_lds16(const void* g, void* l) {
  __builtin_amdgcn_global_load_lds(
      (const __attribute__((address_space(1))) void*)g,
      (__attribute__((address_space(3))) void*)l, 16, 0, 0);
}

__device__ __forceinline__ u16 f2bf(float f) {
  union { float f; unsigned u; } v; v.f = f;
  unsigned r = v.u + 0x7FFFu + ((v.u >> 16) & 1u);
  return (u16)(r >> 16);
}

__device__ __forceinline__ float fast_exp2(float x) {
#if __has_builtin(__builtin_amdgcn_exp2f)
  return __builtin_amdgcn_exp2f(x);
#else
  return exp2f(x);
#endif
}
__device__ __forceinline__ float fast_rcp(float x) {
#if __has_builtin(__builtin_amdgcn_rcpf)
  return __builtin_amdgcn_rcpf(x);
#else
  return 1.f / x;
#endif
}
__device__ __forceinline__ unsigned pk_bf16(float a, float b) {
#if __has_builtin(__builtin_amdgcn_cvt_pk_bf16_f32)
  auto pk = __builtin_amdgcn_cvt_pk_bf16_f32(a, b);
  unsigned u; __builtin_memcpy(&u, &pk, sizeof(u));
  return u;
#else
  return (unsigned)f2bf(a) | ((unsigned)f2bf(b) << 16);
#endif
}

__device__ __forceinline__ float wave_reduce_sum(float v) {
#pragma unroll
  for (int off = 32; off > 0; off >>= 1) v += __shfl_xor(v, off, 64);
  return v;
}

// ---------------- fused prep: convgates blocks + 2 weight transposes ----------------
#define CG_BLOCKS ((NROWS + 3) / 4)          // 4131
#define T1_NB 48
#define T1_BLOCKS (48 * 16)                  // qkv_w 512x1536
#define T2_NB 16
#define T2_BLOCKS (16 * 16)                  // proj_w 512x512

__device__ __forceinline__ void trans_body(const float* __restrict__ in,
                                           u16* __restrict__ out, int K, int N,
                                           int nb, int kb, float (*tile)[33]) {
  int n0 = nb * 32, k0 = kb * 32;
  int tx = threadIdx.x & 31, ty = threadIdx.x >> 5;
#pragma unroll
  for (int p = 0; p < 4; ++p)
    tile[ty + p * 8][tx] = in[(size_t)(k0 + ty + p * 8) * N + n0 + tx];
  __syncthreads();
#pragma unroll
  for (int p = 0; p < 4; ++p)
    out[(size_t)(n0 + ty + p * 8) * K + k0 + tx] = f2bf(tile[tx][ty + p * 8]);
}

__global__ __launch_bounds__(256) void prep_kernel(
    const float* __restrict__ x, const float* __restrict__ te_w,
    const float* __restrict__ te_b, const float* __restrict__ qkv_w,
    const float* __restrict__ proj_w, u16* __restrict__ xb,
    float* __restrict__ gates, u16* __restrict__ wt, u16* __restrict__ pwt) {
  __shared__ float tile[32][33];
  int bid = blockIdx.x;
  if (bid >= CG_BLOCKS) {
    int r = bid - CG_BLOCKS;
    if (r < T1_BLOCKS) trans_body(qkv_w, wt, 512, 1536, r % T1_NB, r / T1_NB, tile);
    else {
      r -= T1_BLOCKS;
      trans_body(proj_w, pwt, 512, 512, r % T2_NB, r / T2_NB, tile);
    }
    return;
  }
  int w = threadIdx.x >> 6, l = threadIdx.x & 63;
  int row = bid * 4 + w;
  if (row >= NROWS) return;
  const float* xr = x + (size_t)row * CDIM;
  u16* xo = xb + (size_t)row * CDIM;
  float a0 = 0.f, a1 = 0.f, a2 = 0.f, a3 = 0.f;
#pragma unroll
  for (int p = 0; p < 2; ++p) {
    int c = (p * 64 + l) * 4;
    float4 v = *(const float4*)(xr + c);
    uint2 o;
    o.x = pk_bf16(v.x, v.y);
    o.y = pk_bf16(v.z, v.w);
    *(uint2*)(xo + c) = o;
    float xv[4] = {v.x, v.y, v.z, v.w};
#pragma unroll
    for (int q = 0; q < 4; ++q) {
      float4 wv = *(const float4*)(te_w + (size_t)(c + q) * 4);
      a0 += xv[q] * wv.x; a1 += xv[q] * wv.y;
      a2 += xv[q] * wv.z; a3 += xv[q] * wv.w;
    }
  }
  a0 = wave_reduce_sum(a0);
  a1 = wave_reduce_sum(a1);
  a2 = wave_reduce_sum(a2);
  a3 = wave_reduce_sum(a3);
  a0 += te_b[0]; a1 += te_b[1]; a2 += te_b[2]; a3 += te_b[3];
  float mx = fmaxf(fmaxf(a0, a1), fmaxf(a2, a3));
  float e0 = __expf(a0 - mx), e1 = __expf(a1 - mx);
  float e2 = __expf(a2 - mx), e3 = __expf(a3 - mx);
  float inv = fast_rcp(e0 + e1 + e2 + e3);
  if (l == 0) {
    *(float4*)(gates + (size_t)row * 4) =
        make_float4(e0 * inv, e1 * inv, e2 * inv, e3 * inv);
  }
}

// ---------------- qkv GEMM (bf16 MFMA), BK=64, XCD-swizzled 1D grid (1560 blocks) ----------------
// 130 r0-slices x 12 n-blocks; blocks with bid%8==X land on XCD X and cover a
// contiguous run of r0 with all n — A slice fetched once per XCD L2.
__global__ __launch_bounds__(256) void qkv_gemm(
    const u16* __restrict__ xb, const u16* __restrict__ wt,
    u16* __restrict__ qh, u16* __restrict__ kh, u16* __restrict__ vb) {
  __shared__ u16 S[16640];   // A [0,8192) + B [8192,16384) | V-transpose stride 130
  u16* Al = S;
  u16* Bl = S + 8192;
  int tid = threadIdx.x;
  int w = tid >> 6;
  int c16 = tid & 15, g4 = (tid >> 4) & 3;
  int bid = blockIdx.x;
  int wrk = (bid & 7) * 195 + (bid >> 3);   // 8 XCDs x 195
  int r0 = (wrk / 12) * 128;
  int n0 = (wrk % 12) * 128;
  int wm = w & 1, wn = w >> 1;

  int rA = tid >> 3;
  int c8off = (((tid & 7) ^ (rA & 7)) * 8);
  size_t arow4[4], brow4[4];
#pragma unroll
  for (int it = 0; it < 4; ++it) {
    int m = r0 + it * 32 + rA;
    if (m >= NROWS) m = NROWS - 1;
    int bj = m / 243, t = m - bj * 243;
    int b = bj / 17, j = bj - b * 17;
    arow4[it] = ((size_t)(b * 243 + t) * 17 + j) * 512;
    brow4[it] = (size_t)(n0 + it * 32 + rA) * 512;
  }

  f32x4 acc[4][4] = {};
  for (int k0 = 0; k0 < CDIM; k0 += 64) {
    __syncthreads();
#pragma unroll
    for (int it = 0; it < 4; ++it) {
      gl_lds16(xb + arow4[it] + k0 + c8off, Al + (size_t)(it * 256 + (w * 64)) * 8);
      gl_lds16(wt + brow4[it] + k0 + c8off, Bl + (size_t)(it * 256 + (w * 64)) * 8);
    }
    __syncthreads();
    short8 af[4][2], bf[4][2];
#pragma unroll
    for (int i = 0; i < 4; ++i) {
      int rowa = wm * 64 + i * 16 + c16;
#pragma unroll
      for (int hh = 0; hh < 2; ++hh)
        af[i][hh] = *(const short8*)(Al + rowa * 64 + (((hh * 4 + g4) ^ (c16 & 7)) * 8));
    }
#pragma unroll
    for (int j = 0; j < 4; ++j) {
      int rowb = wn * 64 + j * 16 + c16;
#pragma unroll
      for (int hh = 0; hh < 2; ++hh)
        bf[j][hh] = *(const short8*)(Bl + rowb * 64 + (((hh * 4 + g4) ^ (c16 & 7)) * 8));
    }
#pragma unroll
    for (int i = 0; i < 4; ++i)
#pragma unroll
      for (int j = 0; j < 4; ++j) {
        acc[i][j] = MFMA16(af[i][0], bf[j][0], acc[i][j]);
        acc[i][j] = MFMA16(af[i][1], bf[j][1], acc[i][j]);
      }
  }

  if (n0 < 1024) {
    // ---- q/k epilogue: direct store to [bhn][t][64]; q pre-scaled by QSCALE
#pragma unroll
    for (int i = 0; i < 4; ++i)
#pragma unroll
      for (int r = 0; r < 4; ++r) {
        int m = r0 + wm * 64 + i * 16 + g4 * 4 + r;
        if (m >= NROWS) continue;
        int bj = m / 243, t = m - bj * 243;
        int b = bj / 17, j = bj - b * 17;
#pragma unroll
        for (int jt = 0; jt < 4; ++jt) {
          int col = n0 + wn * 64 + jt * 16 + c16;
          int sel = col >> 9, h = (col >> 6) & 7, c = col & 63;
          u16* dst = sel ? kh : qh;
          float val = acc[i][jt][r];
          if (!sel) val *= QSCALE;
          dst[((size_t)((b * 8 + h) * 17 + j) * 243 + t) * 64 + c] = f2bf(val);
        }
      }
  } else {
    // ---- V epilogue: transpose C-tile via LDS, store t-contiguous
    __syncthreads();
#pragma unroll
    for (int i = 0; i < 4; ++i)
#pragma unroll
      for (int jt = 0; jt < 4; ++jt)
#pragma unroll
        for (int r = 0; r < 4; ++r) {
          int row = wm * 64 + i * 16 + g4 * 4 + r;
          int colI = wn * 64 + jt * 16 + c16;
          S[colI * 130 + row] = f2bf(acc[i][jt][r]);
        }
    __syncthreads();
    int l = tid & 63;
    int hb = (n0 - 1024) >> 6;
    int m0 = r0 + 2 * l;
    int m1 = m0 + 1;
    bool v0 = m0 < NROWS, v1 = m1 < NROWS;
    int bj0 = m0 / 243, t0 = m0 - bj0 * 243;
    int b0 = bj0 / 17, j0 = bj0 - b0 * 17;
    int bj1 = m1 / 243, t1 = m1 - bj1 * 243;
    int b1 = bj1 / 17, j1 = bj1 - b1 * 17;
    size_t base0 = ((size_t)(b0 * 136 + j0) * 64) * 256 + t0;
    size_t base1 = ((size_t)(b1 * 136 + j1) * 64) * 256 + t1;
#pragma unroll 8
    for (int cc = 0; cc < 32; ++cc) {
      int colI = w * 32 + cc;
      int h = hb + (colI >> 6), c = colI & 63;
      ushort2 u = *(const ushort2*)&S[colI * 130 + 2 * l];
      size_t hoff = ((size_t)h * 17 * 64) * 256 + (size_t)c * 256;
      if (v0) vb[base0 + hoff] = u.x;
      if (v1) vb[base1 + hoff] = u.y;
    }
  }
}

// ---------------- fused attention (bf16 MFMA), S^T orientation ----------------
__global__ __launch_bounds__(256, 4) void attn_kernel(
    const u16* __restrict__ qh, const u16* __restrict__ kh,
    const u16* __restrict__ vb, const float* __restrict__ gates,
    u16* __restrict__ preb) {
  __shared__ u16 L[16384];
  int bhn = blockIdx.x;
  int q0 = blockIdx.y * 64;
  int b = bhn / (NH * NJ);
  int hj = bhn - b * (NH * NJ);
  int h = hj / NJ, j = hj - h * NJ;
  int tid = threadIdx.x;
  int w = tid >> 6;
  int c16 = tid & 15, g4 = (tid >> 4) & 3;
  const u16* Kp = kh + (size_t)bhn * (TT * HD);
  const u16* Qp = qh + (size_t)bhn * (TT * HD);
  const u16* Vp = vb + (size_t)bhn * (HD * 256);
  u16* Rw = L + w * 4096;

  // ---- stage K once, xor-swizzled
#pragma unroll
  for (int it = 0; it < 8; ++it) {
    int F = it * 256 + tid;
    int s = F >> 3;
    int c8 = (F & 7) ^ (s & 7);
    int sg = s < TT ? s : TT - 1;
    gl_lds16(Kp + (size_t)sg * 64 + c8 * 8, L + (size_t)(it * 256 + (tid & ~63)) * 8);
  }
  __syncthreads();   // barrier 1

  int tt = q0 + w * 16 + c16;
  bool tvalid = tt < TT;
  int tg = tvalid ? tt : TT - 1;

  short8 bq[2];
#pragma unroll
  for (int hh = 0; hh < 2; ++hh)
    bq[hh] = *(const short8*)(Qp + (size_t)tg * 64 + hh * 32 + g4 * 8);

  f32x4 acc[16];
#pragma unroll
  for (int st = 0; st < 16; ++st) acc[st] = (f32x4)(0.f);
#pragma unroll
  for (int st = 0; st < 16; ++st) {
    int sf = st * 16 + c16;
#pragma unroll
    for (int hh = 0; hh < 2; ++hh) {
      short8 ak = *(const short8*)(L + sf * 64 + ((hh * 4 + g4) ^ (sf & 7)) * 8);
      acc[st] = MFMA16(ak, bq[hh], acc[st]);
    }
  }
  __syncthreads();   // barrier 2: L becomes R region

  // ---- mask the st=15 tail (s = 240 + g4*4 + r >= 243)
#pragma unroll
  for (int r = 0; r < 4; ++r) {
    int s = 240 + g4 * 4 + r;
    if (s >= TT) acc[15][r] = -1e30f;
  }
  // ---- row max
  float M = -1e30f;
#pragma unroll
  for (int st = 0; st < 16; ++st)
#pragma unroll
    for (int r = 0; r < 4; ++r) M = fmaxf(M, acc[st][r]);
  M = fmaxf(M, __shfl_xor(M, 16, 64));
  M = fmaxf(M, __shfl_xor(M, 32, 64));

  // ---- exp2 (scores already in log2 domain)
#pragma unroll
  for (int st = 0; st < 16; ++st)
#pragma unroll
    for (int r = 0; r < 4; ++r) acc[st][r] = fast_exp2(acc[st][r] - M);

  // ---- nested-window sums: l243 via vector tree, others masked into f32x4 lanes
  int t9b = (tg / 9) * 9;
  int t27b = (tg / 27) * 27;
  int t81b = (tg / 81) * 81;
  f32x4 vall = acc[0];
#pragma unroll
  for (int st = 1; st < 16; ++st) vall += acc[st];
  float l243 = (vall[0] + vall[1]) + (vall[2] + vall[3]);
  f32x4 v81 = (f32x4)(0.f), v27 = (f32x4)(0.f), v9 = (f32x4)(0.f);
#pragma unroll
  for (int st = 0; st < 16; ++st)
#pragma unroll
    for (int r = 0; r < 4; ++r) {
      int s = st * 16 + g4 * 4 + r;
      float e = acc[st][r];
      v81[r] += ((unsigned)(s - t81b) < 81u) ? e : 0.f;
      v27[r] += ((unsigned)(s - t27b) < 27u) ? e : 0.f;
      v9[r]  += ((unsigned)(s - t9b)  <  9u) ? e : 0.f;
    }
  float l81 = (v81[0] + v81[1]) + (v81[2] + v81[3]);
  float l27 = (v27[0] + v27[1]) + (v27[2] + v27[3]);
  float l9  = (v9[0] + v9[1]) + (v9[2] + v9[3]);
  l9   += __shfl_xor(l9, 16, 64);   l9   += __shfl_xor(l9, 32, 64);
  l27  += __shfl_xor(l27, 16, 64);  l27  += __shfl_xor(l27, 32, 64);
  l81  += __shfl_xor(l81, 16, 64);  l81  += __shfl_xor(l81, 32, 64);
  l243 += __shfl_xor(l243, 16, 64); l243 += __shfl_xor(l243, 32, 64);

  float4 gv = *(const float4*)(gates + ((size_t)(b * TT + tg) * NJ + j) * 4);
  float gam3 = gv.w * fast_rcp(l243);
  float gam2 = gam3 + gv.z * fast_rcp(l81);
  float gam1 = gam2 + gv.y * fast_rcp(l27);
  float gam0 = gam1 + gv.x * fast_rcp(l9);
  if (!tvalid) { gam0 = 0.f; gam1 = 0.f; gam2 = 0.f; gam3 = 0.f; }

  // ---- combined weights R[t][s] -> wave-private LDS, packed b64 writes
#pragma unroll
  for (int st = 0; st < 16; ++st) {
    float rv[4];
#pragma unroll
    for (int r = 0; r < 4; ++r) {
      int s = st * 16 + g4 * 4 + r;
      float e = acc[st][r];
      float cw = ((unsigned)(s - t9b) < 9u) ? gam0
               : ((unsigned)(s - t27b) < 27u) ? gam1
               : ((unsigned)(s - t81b) < 81u) ? gam2 : gam3;
      rv[r] = e * cw;
    }
    uint2 pk;
    pk.x = pk_bf16(rv[0], rv[1]);
    pk.y = pk_bf16(rv[2], rv[3]);
    int c8 = st * 2 + (g4 >> 1);
    int slot = (c8 & 24) | ((c8 & 7) ^ (c16 & 7));
    *(uint2*)(Rw + c16 * 256 + slot * 8 + (g4 & 1) * 4) = pk;
  }
  // no barrier: Rw is wave-private

  // ---- PV: O[16t][64c] = R[16][256] @ V[256][64]
  short8 ar[8];
#pragma unroll
  for (int h2 = 0; h2 < 8; ++h2) {
    int cc = h2 * 4 + g4;
    int slot = (cc & 24) | ((cc & 7) ^ (c16 & 7));
    ar[h2] = *(const short8*)(Rw + c16 * 256 + slot * 8);
  }
#pragma unroll
  for (int jt = 0; jt < 4; ++jt) {
    int c = jt * 16 + c16;
    f32x4 o = (f32x4)(0.f);
#pragma unroll
    for (int h2 = 0; h2 < 8; ++h2) {
      short8 bv = *(const short8*)(Vp + (size_t)c * 256 + h2 * 32 + g4 * 8);
      o = MFMA16(ar[h2], bv, o);
    }
#pragma unroll
    for (int r = 0; r < 4; ++r) {
      int t = q0 + w * 16 + g4 * 4 + r;
      if (t < TT)
        preb[((size_t)(b * TT + t) * NJ + j) * 512 + h * 64 + c] = f2bf(o[r]);
    }
  }
}

// ---------------- proj GEMM (bf16 MFMA), BK=64, XCD-swizzled 1D grid (520 blocks) ----------------
__global__ __launch_bounds__(256) void proj_gemm(
    const u16* __restrict__ preb, const u16* __restrict__ pwt,
    const float* __restrict__ bias, float* __restrict__ out) {
  __shared__ u16 Al[8192];
  __shared__ u16 Bl[8192];
  int tid = threadIdx.x;
  int w = tid >> 6;
  int c16 = tid & 15, g4 = (tid >> 4) & 3;
  int bid = blockIdx.x;
  int wrk = (bid & 7) * 65 + (bid >> 3);    // 8 XCDs x 65
  int r0 = (wrk >> 2) * 128;
  int n0 = (wrk & 3) * 128;
  int wm = w & 1, wn = w >> 1;

  int rA = tid >> 3;
  int c8off = (((tid & 7) ^ (rA & 7)) * 8);
  size_t arow4[4], brow4[4];
#pragma unroll
  for (int it = 0; it < 4; ++it) {
    int m = r0 + it * 32 + rA;
    if (m >= NROWS) m = NROWS - 1;
    arow4[it] = (size_t)m * 512;
    brow4[it] = (size_t)(n0 + it * 32 + rA) * 512;
  }

  f32x4 acc[4][4] = {};
  for (int k0 = 0; k0 < CDIM; k0 += 64) {
    __syncthreads();
#pragma unroll
    for (int it = 0; it < 4; ++it) {
      gl_lds16(preb + arow4[it] + k0 + c8off, Al + (size_t)(it * 256 + (w * 64)) * 8);
      gl_lds16(pwt + brow4[it] + k0 + c8off, Bl + (size_t)(it * 256 + (w * 64)) * 8);
    }
    __syncthreads();
    short8 af[4][2], bf[4][2];
#pragma unroll
    for (int i = 0; i < 4; ++i) {
      int rowa = wm * 64 + i * 16 + c16;
#pragma unroll
      for (int hh = 0; hh < 2; ++hh)
        af[i][hh] = *(const short8*)(Al + rowa * 64 + (((hh * 4 + g4) ^ (c16 & 7)) * 8));
    }
#pragma unroll
    for (int j = 0; j < 4; ++j) {
      int rowb = wn * 64 + j * 16 + c16;
#pragma unroll
      for (int hh = 0; hh < 2; ++hh)
        bf[j][hh] = *(const short8*)(Bl + rowb * 64 + (((hh * 4 + g4) ^ (c16 & 7)) * 8));
    }
#pragma unroll
    for (int i = 0; i < 4; ++i)
#pragma unroll
      for (int j = 0; j < 4; ++j) {
        acc[i][j] = MFMA16(af[i][0], bf[j][0], acc[i][j]);
        acc[i][j] = MFMA16(af[i][1], bf[j][1], acc[i][j]);
      }
  }
#pragma unroll
  for (int i = 0; i < 4; ++i)
#pragma unroll
    for (int r = 0; r < 4; ++r) {
      int row = r0 + wm * 64 + i * 16 + g4 * 4 + r;
      if (row >= NROWS) continue;
#pragma unroll
      for (int jt = 0; jt < 4; ++jt) {
        int col = n0 + wn * 64 + jt * 16 + c16;
        out[(size_t)row * 512 + col] = acc[i][jt][r] + bias[col];
      }
    }
}

extern "C" void kernel_launch(void* const* d_in, const int* in_sizes, int n_in,
                              void* d_out, int out_size, void* d_ws, size_t ws_size,
                              hipStream_t stream) {
  (void)in_sizes; (void)n_in; (void)out_size; (void)ws_size;
  const float* x      = (const float*)d_in[0];
  const float* qkv_w  = (const float*)d_in[1];
  const float* proj_w = (const float*)d_in[2];
  const float* proj_b = (const float*)d_in[3];
  const float* te_w   = (const float*)d_in[4];
  const float* te_b   = (const float*)d_in[5];

  char* p = (char*)d_ws;
  auto alloc = [&](size_t bytes) {
    void* r = (void*)p;
    p += (bytes + 255) & ~(size_t)255;
    return r;
  };
  u16*   xb    = (u16*)alloc((size_t)NROWS * 512 * 2);
  u16*   wt    = (u16*)alloc((size_t)1536 * 512 * 2);
  u16*   pwt   = (u16*)alloc((size_t)512 * 512 * 2);
  float* gates = (float*)alloc((size_t)NROWS * 4 * 4);
  u16*   qhb   = (u16*)alloc((size_t)NBHN * 243 * 64 * 2);
  u16*   khb   = (u16*)alloc((size_t)NBHN * 243 * 64 * 2);
  u16*   vb    = (u16*)alloc((size_t)NBHN * 64 * 256 * 2);
  u16*   preb  = (u16*)alloc((size_t)NROWS * 512 * 2);
  float* out   = (float*)d_out;

  hipLaunchKernelGGL(prep_kernel, dim3(CG_BLOCKS + T1_BLOCKS + T2_BLOCKS), dim3(256),
                     0, stream, x, te_w, te_b, qkv_w, proj_w, xb, gates, wt, pwt);
  hipLaunchKernelGGL(qkv_gemm, dim3(1560), dim3(256), 0, stream,
                     xb, wt, qhb, khb, vb);
  hipLaunchKernelGGL(attn_kernel, dim3(NBHN, 4), dim3(256), 0, stream,
                     qhb, khb, vb, gates, preb);
  hipLaunchKernelGGL(proj_gemm, dim3(520), dim3(256), 0, stream,
                     preb, pwt, proj_b, out);
}